// Round 10
// baseline (1071.297 us; speedup 1.0000x reference)
//
#include <hip/hip_runtime.h>
#include <hip/hip_bf16.h>

// ---------------------------------------------------------------------------
// QLSTMCell MI355X round 10: SINGLE fused kernel.
//  - fp32 inputs read directly; fp32->bf16 cvt fused into reg-staging
//    (global_load fp32 -> VGPR -> cvt -> swizzled ds_write_b128)
//  - W gate-permutation folded into staging address math (no W' tensor)
//  - ONE barrier per K-tile; counted lgkm/vmcnt; LDS reads/writes overlap MFMA
//  - read path, XOR swizzle, epilogue identical to R9 (refcheck'd twice)
// vmcnt LEDGER (4 dwordx4 per sub-batch; FIFO):
//   tile t stages tile t+1 into bufn: issue bA1,bB1 (8) at top;
//   after MFMA1: vmcnt(4)->bA1 done, write, issue bA2 (back to 8);
//                vmcnt(4)->bB1 done, write, issue bB2 (8);
//   after MFMA2: vmcnt(4)->bA2 done, write; vmcnt(0)->bB2 done, write;
//   lgkmcnt(0) drains ds_writes before the next tile-top barrier.
// WAR: writes target bufn; all reads of bufn's previous contents were drained
//   by lgkmcnt(0) before the previous tile's MFMA2, which precedes the barrier.
// ---------------------------------------------------------------------------

typedef __attribute__((ext_vector_type(8))) short short8;   // 8 x bf16
typedef __attribute__((ext_vector_type(4))) float f32x4;    // MFMA accum

#define B_SZ 4096
#define K_SZ 4096      // IN + H
#define N_SZ 8192      // 4*H
#define H_SZ 2048

__device__ __forceinline__ float hsig(float x) {
    return fminf(fmaxf(x * (1.0f / 6.0f) + 0.5f, 0.0f), 1.0f);
}
__device__ __forceinline__ float htanh(float x) {
    return fminf(fmaxf(x, -1.0f), 1.0f);
}

__device__ __forceinline__ uint4 pack8(float4 lo, float4 hi) {
    union { __hip_bfloat16 h[8]; uint4 q; } p;
    p.h[0] = __float2bfloat16(lo.x); p.h[1] = __float2bfloat16(lo.y);
    p.h[2] = __float2bfloat16(lo.z); p.h[3] = __float2bfloat16(lo.w);
    p.h[4] = __float2bfloat16(hi.x); p.h[5] = __float2bfloat16(hi.y);
    p.h[6] = __float2bfloat16(hi.z); p.h[7] = __float2bfloat16(hi.w);
    return p.q;
}

// ---- fused cvt + GEMM + LSTM cell ------------------------------------------
__global__ __launch_bounds__(512, 2)
void gemm_fused_kernel(const float* __restrict__ x,
                       const float* __restrict__ h0,
                       const float* __restrict__ wih,
                       const float* __restrict__ whh,
                       const float* __restrict__ c0,
                       const float* __restrict__ bias,
                       float* __restrict__ out)
{
    constexpr int BK = 64;
    constexpr int NT = K_SZ / BK;            // 64 K-tiles
    constexpr int NWG = (B_SZ / 256) * (N_SZ / 256);  // 512
    constexpr int TILEB = 65536;             // A 32KB + B 32KB (bf16)

    extern __shared__ __align__(16) char lds[];   // 2 * TILEB = 128KB

    const int tid  = threadIdx.x;
    const int wave = tid >> 6;
    const int lane = tid & 63;
    const int wrow = wave >> 2;        // 0..1
    const int wcol = wave & 3;         // 0..3
    const int fr   = lane & 15;
    const int fkq  = lane >> 4;

    // XCD-aware bijective swizzle (NWG = 512, %8==0)
    int bid = blockIdx.x;
    int swz = (bid & 7) * (NWG / 8) + (bid >> 3);
    int bm = swz >> 5;                 // 0..15
    int bn = swz & 31;                 // 0..31

    // ---- staging constants (thread -> 8 chunks/tile, 4 sub-batches) --------
    const int rs = tid >> 3;           // 0..63
    const int ch = tid & 7;
    // A global element offset base (row bm*256+rs, chunk ch): +k*131072 per 64 rows
    const int abase = (bm * 256 + rs) * 2048 + ch * 8;
    // B global element offsets via gate permutation (4 rows: rs + k*64)
    int boff[4];
#pragma unroll
    for (int k = 0; k < 4; ++k) {
        int br = rs + k * 64;          // B-tile local row
        int gate = (((br >> 7) & 1) << 1) | ((br >> 4) & 1);
        int j = (br & 15) | (((br >> 5) & 3) << 4) | (bn << 6);
        boff[k] = (gate * 2048 + j) * 2048 + ch * 8;
    }
    // LDS write dest base (swizzled chunk; row&7 == rs&7 for all k)
    const int adst = rs * 128 + ((ch ^ (rs & 7)) << 4);

    // ---- swizzled ds_read byte offsets (ks=0); ks=1 is ^64, mh/nh is +16384
    int a_off[4], b_off[2];
#pragma unroll
    for (int mf = 0; mf < 4; ++mf) {
        int row = wrow * 64 + mf * 16 + fr;
        a_off[mf] = row * 128 + ((fkq ^ (row & 7)) << 4);
    }
#pragma unroll
    for (int nf = 0; nf < 2; ++nf) {
        int row = wcol * 32 + nf * 16 + fr;
        b_off[nf] = row * 128 + ((fkq ^ (row & 7)) << 4);
    }

    f32x4 acc[8][4];
#pragma unroll
    for (int m = 0; m < 8; ++m)
#pragma unroll
        for (int n = 0; n < 4; ++n)
            acc[m][n] = f32x4{0.f, 0.f, 0.f, 0.f};

    float4 aL0, aH0, aL1, aH1;    // A sub-batch regs (reused bA1/bA2)
    float4 bL0, bH0, bL1, bH1;    // B sub-batch regs (reused bB1/bB2)

#define LD_A(k0) { \
    const float* p0 = As + abase + (k0) * 131072 + kc; \
    const float* p1 = As + abase + ((k0) + 1) * 131072 + kc; \
    aL0 = *(const float4*)(p0); aH0 = *(const float4*)(p0 + 4); \
    aL1 = *(const float4*)(p1); aH1 = *(const float4*)(p1 + 4); }
#define LD_B(k0) { \
    const float* p0 = Ws + boff[k0] + kc; \
    const float* p1 = Ws + boff[(k0) + 1] + kc; \
    bL0 = *(const float4*)(p0); bH0 = *(const float4*)(p0 + 4); \
    bL1 = *(const float4*)(p1); bH1 = *(const float4*)(p1 + 4); }
#define WR_A(k0) { \
    *(uint4*)(bufn + adst + (k0) * 8192) = pack8(aL0, aH0); \
    *(uint4*)(bufn + adst + ((k0) + 1) * 8192) = pack8(aL1, aH1); }
#define WR_B(k0) { \
    *(uint4*)(bufn + 32768 + adst + (k0) * 8192) = pack8(bL0, bH0); \
    *(uint4*)(bufn + 32768 + adst + ((k0) + 1) * 8192) = pack8(bL1, bH1); }

    // ---- prologue: stage tile 0 into buf0 ----------------------------------
    {
        char* bufn = lds;
        const float* As = x;           // kt=0 < 2048
        const float* Ws = wih;
        const int kc = 0;
        LD_A(0); LD_B(0);
        asm volatile("s_waitcnt vmcnt(4)" ::: "memory");
        WR_A(0); LD_A(2);
        asm volatile("s_waitcnt vmcnt(4)" ::: "memory");
        WR_B(0); LD_B(2);
        asm volatile("s_waitcnt vmcnt(4)" ::: "memory");
        WR_A(2);
        asm volatile("s_waitcnt vmcnt(0)" ::: "memory");
        WR_B(2);
        asm volatile("s_waitcnt lgkmcnt(0)" ::: "memory");
    }

#pragma unroll 1
    for (int t = 0; t < NT; ++t) {
        char* bufc = lds + (t & 1) * TILEB;
        char* bufn = lds + ((t + 1) & 1) * TILEB;
        const char* Ab = bufc;
        const char* Bb = bufc + 32768;
        const bool st = (t + 1 < NT);
        const int knext = (t + 1) * BK;
        const bool inx = knext < 2048;
        const float* As = inx ? x : h0;
        const float* Ws = inx ? wih : whh;
        const int kc = knext & 2047;

        asm volatile("s_barrier" ::: "memory");       // bufc staged & visible

        if (st) { LD_A(0); LD_B(0); }                 // vm: 8 outstanding

        // R0: A-mh0 + B-nh0 + B-nh1 (16 ds_reads)
        short8 av[4][2], bv0[2][2], bv1[2][2];
#pragma unroll
        for (int mf = 0; mf < 4; ++mf)
#pragma unroll
            for (int ks = 0; ks < 2; ++ks)
                av[mf][ks] = *(const short8*)(Ab + (a_off[mf] ^ (ks << 6)));
#pragma unroll
        for (int nf = 0; nf < 2; ++nf)
#pragma unroll
            for (int ks = 0; ks < 2; ++ks) {
                bv0[nf][ks] = *(const short8*)(Bb + (b_off[nf] ^ (ks << 6)));
                bv1[nf][ks] = *(const short8*)(Bb + 16384 + (b_off[nf] ^ (ks << 6)));
            }
        asm volatile("s_waitcnt lgkmcnt(0)" ::: "memory");
        __builtin_amdgcn_sched_barrier(0);
        __builtin_amdgcn_s_setprio(1);
#pragma unroll
        for (int mf = 0; mf < 4; ++mf)
#pragma unroll
            for (int nf = 0; nf < 2; ++nf)
#pragma unroll
                for (int ks = 0; ks < 2; ++ks) {
                    acc[mf][nf]     = __builtin_amdgcn_mfma_f32_16x16x32_bf16(av[mf][ks], bv0[nf][ks], acc[mf][nf], 0, 0, 0);
                    acc[mf][2 + nf] = __builtin_amdgcn_mfma_f32_16x16x32_bf16(av[mf][ks], bv1[nf][ks], acc[mf][2 + nf], 0, 0, 0);
                }
        __builtin_amdgcn_s_setprio(0);

        if (st) {
            asm volatile("s_waitcnt vmcnt(4)" ::: "memory");   // bA1 landed
            __builtin_amdgcn_sched_barrier(0);
            WR_A(0); LD_A(2);
            asm volatile("s_waitcnt vmcnt(4)" ::: "memory");   // bB1 landed
            __builtin_amdgcn_sched_barrier(0);
            WR_B(0); LD_B(2);
        }

        // R1: A-mh1 (8 ds_reads) — lands under the write block + wait
        short8 aw[4][2];
#pragma unroll
        for (int mf = 0; mf < 4; ++mf)
#pragma unroll
            for (int ks = 0; ks < 2; ++ks)
                aw[mf][ks] = *(const short8*)(Ab + 16384 + (a_off[mf] ^ (ks << 6)));
        asm volatile("s_waitcnt lgkmcnt(0)" ::: "memory");     // R1 + ds_writes
        __builtin_amdgcn_sched_barrier(0);
        __builtin_amdgcn_s_setprio(1);
#pragma unroll
        for (int mf = 0; mf < 4; ++mf)
#pragma unroll
            for (int nf = 0; nf < 2; ++nf)
#pragma unroll
                for (int ks = 0; ks < 2; ++ks) {
                    acc[4 + mf][nf]     = __builtin_amdgcn_mfma_f32_16x16x32_bf16(aw[mf][ks], bv0[nf][ks], acc[4 + mf][nf], 0, 0, 0);
                    acc[4 + mf][2 + nf] = __builtin_amdgcn_mfma_f32_16x16x32_bf16(aw[mf][ks], bv1[nf][ks], acc[4 + mf][2 + nf], 0, 0, 0);
                }
        __builtin_amdgcn_s_setprio(0);

        if (st) {
            asm volatile("s_waitcnt vmcnt(4)" ::: "memory");   // bA2 landed
            __builtin_amdgcn_sched_barrier(0);
            WR_A(2);
            asm volatile("s_waitcnt vmcnt(0)" ::: "memory");   // bB2 landed
            __builtin_amdgcn_sched_barrier(0);
            WR_B(2);
            asm volatile("s_waitcnt lgkmcnt(0)" ::: "memory"); // writes drained
        }
    }
#undef LD_A
#undef LD_B
#undef WR_A
#undef WR_B

    // ---- fused LSTM-cell epilogue (acc n-index == gate: 0=f,1=i,2=o,3=g) ---
    const int jj = bn * 64 + wcol * 16 + fr;         // 0..2047
    const float bf = bias[jj];
    const float bi = bias[2048 + jj];
    const float bo = bias[4096 + jj];
    const float bg = bias[6144 + jj];
    float* h1out = out;
    float* c1out = out + (size_t)B_SZ * H_SZ;
#pragma unroll
    for (int mh = 0; mh < 2; ++mh)
#pragma unroll
        for (int mf = 0; mf < 4; ++mf) {
            const int m = mh * 4 + mf;
            const int row0 = bm * 256 + mh * 128 + wrow * 64 + mf * 16 + fkq * 4;
#pragma unroll
            for (int i = 0; i < 4; ++i) {
                int r = row0 + i;
                float c0v = c0[(size_t)r * H_SZ + jj];
                float f  = acc[m][0][i] + bf;
                float ig = acc[m][1][i] + bi;
                float o  = acc[m][2][i] + bo;
                float g  = acc[m][3][i] + bg;
                float cn = hsig(f) * c0v + hsig(ig) * htanh(g);
                h1out[(size_t)r * H_SZ + jj] = hsig(o) * htanh(cn);
                c1out[(size_t)r * H_SZ + jj] = cn;
            }
        }
}

// ---------------------------------------------------------------------------
extern "C" void kernel_launch(void* const* d_in, const int* in_sizes, int n_in,
                              void* d_out, int out_size, void* d_ws, size_t ws_size,
                              hipStream_t stream)
{
    const float* x   = (const float*)d_in[0];  // [4096,2048]
    const float* h0  = (const float*)d_in[1];  // [4096,2048]
    const float* c0  = (const float*)d_in[2];  // [4096,2048]
    const float* Wih = (const float*)d_in[3];  // [8192,2048]
    const float* Whh = (const float*)d_in[4];  // [8192,2048]
    const float* bhh = (const float*)d_in[5];  // [8192]
    float* out = (float*)d_out;                // h1 (8M) ++ c1 (8M) fp32

    // no workspace needed — everything fused into one kernel
    gemm_fused_kernel<<<512, 512, 131072, stream>>>(x, h0, Wih, Whh, c0, bhh, out);
}

// Round 12
// 490.899 us; speedup vs baseline: 2.1823x; 2.1823x over previous
//
#include <hip/hip_runtime.h>
#include <hip/hip_bf16.h>

// ---------------------------------------------------------------------------
// QLSTMCell MI355X round 12 (= round 11 resubmitted after acquisition timeout):
//  - GEMM: R9 read-path/registers, phases merged 4->2 per K-tile (4 barriers),
//    full-tile prefetch with re-derived counted-vmcnt ledger (no mid-tile stall)
//  - cvts fused into ONE grid-stride kernel (2048 blocks)
// vmcnt LEDGER (1 gload per stage unit; 8 units/tile; FIFO):
//   phaseA(t) issues for t+1 in order: a0,a1,b0,b1,b2,b3,a2,a3
//   needs: phaseA(t) reads {a0,a1,b0..b3}(t); phaseB(t) reads {a2,a3}(t)
//   end-A(t): outstanding = a2,a3(t) + 8(t+1) = 10 -> vmcnt(8) retires a2,a3(t)
//             (issued one full tile earlier: no stall)
//   end-B(t): outstanding = 8(t+1) -> vmcnt(2) retires a0,a1,b0..b3(t+1)
//             (issued ~1 phase earlier; L2-hit latency covered by MFMA)
//   prologue: stage tile0 same order; vmcnt(2); barrier.
//   last tile: no issues; end-A vmcnt(0); end-B no wait.
// WAR: phaseA(t) writes bufn=(t+1)&1, last read as bufc in tile t-1; those
//   reads were drained by lgkmcnt(0) before MFMA-B(t-1) which precedes the
//   end-B(t-1) barrier that precedes these issues. Cross-wave visibility:
//   each wave's vmcnt retire precedes the barrier that precedes any read.
// ---------------------------------------------------------------------------

typedef __attribute__((ext_vector_type(8))) short short8;   // 8 x bf16
typedef __attribute__((ext_vector_type(4))) float f32x4;    // MFMA accum

#define B_SZ 4096
#define K_SZ 4096      // IN + H
#define N_SZ 8192      // 4*H
#define H_SZ 2048

typedef const __attribute__((address_space(1))) void gvoid_t;
typedef __attribute__((address_space(3))) void lvoid_t;

__device__ __forceinline__ void gload_lds16(const __hip_bfloat16* g, void* l) {
    // LDS dest is wave-uniform base; HW adds lane*16
    __builtin_amdgcn_global_load_lds((gvoid_t*)g, (lvoid_t*)l, 16, 0, 0);
}

__device__ __forceinline__ float hsig(float x) {
    return fminf(fmaxf(x * (1.0f / 6.0f) + 0.5f, 0.0f), 1.0f);
}
__device__ __forceinline__ float htanh(float x) {
    return fminf(fmaxf(x, -1.0f), 1.0f);
}

__device__ __forceinline__ void cvt8_store(const float* src, __hip_bfloat16* dst) {
    float4 v0 = *reinterpret_cast<const float4*>(src);
    float4 v1 = *reinterpret_cast<const float4*>(src + 4);
    union { __hip_bfloat16 h[8]; uint4 q; } p;
    p.h[0] = __float2bfloat16(v0.x); p.h[1] = __float2bfloat16(v0.y);
    p.h[2] = __float2bfloat16(v0.z); p.h[3] = __float2bfloat16(v0.w);
    p.h[4] = __float2bfloat16(v1.x); p.h[5] = __float2bfloat16(v1.y);
    p.h[6] = __float2bfloat16(v1.z); p.h[7] = __float2bfloat16(v1.w);
    *reinterpret_cast<uint4*>(dst) = p.q;
}

// ---- single fused cvt kernel: X' = cvt([x|h0]); W' = cvt(gate-perm [Wih|Whh])
// W' perm: out row r has gate=((r>>7)&1)*2+((r>>4)&1), j=(r&15)|(((r>>5)&3)<<4)|((r>>8)<<6)
__global__ void cvt_all_kernel(const float* __restrict__ x,
                               const float* __restrict__ h0,
                               const float* __restrict__ wih,
                               const float* __restrict__ whh,
                               __hip_bfloat16* __restrict__ Xp,
                               __hip_bfloat16* __restrict__ Wp)
{
    constexpr int XT = B_SZ * K_SZ / 8;   // 2M units
    constexpr int WT = N_SZ * K_SZ / 8;   // 4M units
    const int stride = gridDim.x * blockDim.x;
    for (int i = blockIdx.x * blockDim.x + threadIdx.x; i < XT + WT; i += stride) {
        if (i < XT) {
            int idx = i << 3;
            int r = idx >> 12;
            int c = idx & 4095;           // 8-aligned, never straddles seam
            const float* src = (c < 2048) ? (x + (size_t)r * 2048 + c)
                                          : (h0 + (size_t)r * 2048 + (c - 2048));
            cvt8_store(src, Xp + idx);
        } else {
            int idx = (i - XT) << 3;
            int r = idx >> 12;
            int c = idx & 4095;
            int gate = (((r >> 7) & 1) << 1) | ((r >> 4) & 1);
            int j = (r & 15) | (((r >> 5) & 3) << 4) | ((r >> 8) << 6);
            int srow = gate * 2048 + j;
            const float* src = (c < 2048) ? (wih + (size_t)srow * 2048 + c)
                                          : (whh + (size_t)srow * 2048 + (c - 2048));
            cvt8_store(src, Wp + idx);
        }
    }
}

// ---- fused GEMM + LSTM cell, 8-wave 256^2, 2-phase counted-vmcnt schedule --
__global__ __launch_bounds__(512, 2)
void gemm_fused_kernel(const __hip_bfloat16* __restrict__ A,
                       const __hip_bfloat16* __restrict__ Bw,
                       const float* __restrict__ c0,
                       const float* __restrict__ bias,
                       float* __restrict__ out)
{
    constexpr int BK = 64;
    constexpr int NT = K_SZ / BK;            // 64 K-tiles
    constexpr int NWG = (B_SZ / 256) * (N_SZ / 256);  // 512
    constexpr int TILEB = 65536;             // A 32KB + B 32KB per buffer

    extern __shared__ __align__(16) char lds[];   // 2 * TILEB = 128KB dynamic

    const int tid  = threadIdx.x;
    const int wave = tid >> 6;
    const int lane = tid & 63;
    const int wrow = wave >> 2;        // 0..1
    const int wcol = wave & 3;         // 0..3
    const int fr   = lane & 15;
    const int fkq  = lane >> 4;

    // XCD-aware bijective swizzle (NWG = 512, %8==0)
    int bid = blockIdx.x;
    int swz = (bid & 7) * (NWG / 8) + (bid >> 3);
    int bm = swz >> 5;                 // 0..15
    int bn = swz & 31;                 // 0..31

    // ---- staging (linear LDS dest; inverse-swizzled global source) ---------
    const int rs  = tid >> 3;          // 0..63 row within 64-row stage unit
    const int ch  = tid & 7;
    const int lch = ch ^ (rs & 7);
    const __hip_bfloat16* pa = A  + (size_t)(bm * 256 + rs) * K_SZ + lch * 8;
    const __hip_bfloat16* pb = Bw + (size_t)(bn * 256 + rs) * K_SZ + lch * 8;

#define STG_A(bufn, kt, srow) \
    gload_lds16(pa + (size_t)(srow) * K_SZ + (kt), (bufn) + (srow) * 128 + wave * 1024)
#define STG_B(bufn, kt, srow) \
    gload_lds16(pb + (size_t)(srow) * K_SZ + (kt), (bufn) + 32768 + (srow) * 128 + wave * 1024)
// issue all 8 stage units for the next tile, ledger order a0,a1,b0..b3,a2,a3
#define STG_TILE(bufn, kt) { \
    STG_A(bufn, kt, 0);   STG_A(bufn, kt, 64); \
    STG_B(bufn, kt, 0);   STG_B(bufn, kt, 64); \
    STG_B(bufn, kt, 128); STG_B(bufn, kt, 192); \
    STG_A(bufn, kt, 128); STG_A(bufn, kt, 192); }

    // ---- swizzled ds_read byte offsets (ks=0); ks=1 is ^64, mh/nh is +16384
    int a_off[4], b_off[2];
#pragma unroll
    for (int mf = 0; mf < 4; ++mf) {
        int row = wrow * 64 + mf * 16 + fr;
        a_off[mf] = row * 128 + ((fkq ^ (row & 7)) << 4);
    }
#pragma unroll
    for (int nf = 0; nf < 2; ++nf) {
        int row = wcol * 32 + nf * 16 + fr;
        b_off[nf] = row * 128 + ((fkq ^ (row & 7)) << 4);
    }

    f32x4 acc[8][4];
#pragma unroll
    for (int m = 0; m < 8; ++m)
#pragma unroll
        for (int n = 0; n < 4; ++n)
            acc[m][n] = f32x4{0.f, 0.f, 0.f, 0.f};

    // ---- prologue: stage tile 0; first 6 units resident ---------------------
    STG_TILE(lds, 0);
    asm volatile("s_waitcnt vmcnt(2)" ::: "memory");   // a0,a1,b0..b3 resident
    asm volatile("s_barrier" ::: "memory");

#pragma unroll 1
    for (int t = 0; t < NT; ++t) {
        char* bufc = lds + (t & 1) * TILEB;
        char* bufn = lds + ((t + 1) & 1) * TILEB;
        const char* Ab = bufc;
        const char* Bb = bufc + 32768;
        const int ktn = (t + 1) * BK;
        const bool st = (t + 1 < NT);

        // ======== phase A: reads {A-mh0, B-nh0, B-nh1}; 32 MFMA (mh0 x all n)
        short8 av[4][2], bv0[2][2], bv1[2][2];
#pragma unroll
        for (int mf = 0; mf < 4; ++mf)
#pragma unroll
            for (int ks = 0; ks < 2; ++ks)
                av[mf][ks] = *(const short8*)(Ab + (a_off[mf] ^ (ks << 6)));
#pragma unroll
        for (int nf = 0; nf < 2; ++nf)
#pragma unroll
            for (int ks = 0; ks < 2; ++ks) {
                bv0[nf][ks] = *(const short8*)(Bb + (b_off[nf] ^ (ks << 6)));
                bv1[nf][ks] = *(const short8*)(Bb + 16384 + (b_off[nf] ^ (ks << 6)));
            }
        if (st) STG_TILE(bufn, ktn);
        asm volatile("s_barrier" ::: "memory");
        asm volatile("s_waitcnt lgkmcnt(0)" ::: "memory");
        __builtin_amdgcn_sched_barrier(0);
        __builtin_amdgcn_s_setprio(1);
#pragma unroll
        for (int mf = 0; mf < 4; ++mf)
#pragma unroll
            for (int nf = 0; nf < 2; ++nf)
#pragma unroll
                for (int ks = 0; ks < 2; ++ks) {
                    acc[mf][nf]     = __builtin_amdgcn_mfma_f32_16x16x32_bf16(av[mf][ks], bv0[nf][ks], acc[mf][nf], 0, 0, 0);
                    acc[mf][2 + nf] = __builtin_amdgcn_mfma_f32_16x16x32_bf16(av[mf][ks], bv1[nf][ks], acc[mf][2 + nf], 0, 0, 0);
                }
        __builtin_amdgcn_s_setprio(0);
        if (st) asm volatile("s_waitcnt vmcnt(8)" ::: "memory");  // retire a2,a3(t)
        else    asm volatile("s_waitcnt vmcnt(0)" ::: "memory");
        asm volatile("s_barrier" ::: "memory");

        // ======== phase B: reads {A-mh1}; 32 MFMA (mh1 x all n) ==============
        short8 aw[4][2];
#pragma unroll
        for (int mf = 0; mf < 4; ++mf)
#pragma unroll
            for (int ks = 0; ks < 2; ++ks)
                aw[mf][ks] = *(const short8*)(Ab + 16384 + (a_off[mf] ^ (ks << 6)));
        asm volatile("s_barrier" ::: "memory");
        asm volatile("s_waitcnt lgkmcnt(0)" ::: "memory");
        __builtin_amdgcn_sched_barrier(0);
        __builtin_amdgcn_s_setprio(1);
#pragma unroll
        for (int mf = 0; mf < 4; ++mf)
#pragma unroll
            for (int nf = 0; nf < 2; ++nf)
#pragma unroll
                for (int ks = 0; ks < 2; ++ks) {
                    acc[4 + mf][nf]     = __builtin_amdgcn_mfma_f32_16x16x32_bf16(aw[mf][ks], bv0[nf][ks], acc[4 + mf][nf], 0, 0, 0);
                    acc[4 + mf][2 + nf] = __builtin_amdgcn_mfma_f32_16x16x32_bf16(aw[mf][ks], bv1[nf][ks], acc[4 + mf][2 + nf], 0, 0, 0);
                }
        __builtin_amdgcn_s_setprio(0);
        if (st) asm volatile("s_waitcnt vmcnt(2)" ::: "memory");  // retire a0,a1,b(t+1)
        asm volatile("s_barrier" ::: "memory");
    }
#undef STG_A
#undef STG_B
#undef STG_TILE

    // ---- fused LSTM-cell epilogue (acc n-index == gate: 0=f,1=i,2=o,3=g) ---
    const int jj = bn * 64 + wcol * 16 + fr;         // 0..2047
    const float bf = bias[jj];
    const float bi = bias[2048 + jj];
    const float bo = bias[4096 + jj];
    const float bg = bias[6144 + jj];
    float* h1out = out;
    float* c1out = out + (size_t)B_SZ * H_SZ;
#pragma unroll
    for (int mh = 0; mh < 2; ++mh)
#pragma unroll
        for (int mf = 0; mf < 4; ++mf) {
            const int m = mh * 4 + mf;
            const int row0 = bm * 256 + mh * 128 + wrow * 64 + mf * 16 + fkq * 4;
#pragma unroll
            for (int i = 0; i < 4; ++i) {
                int r = row0 + i;
                float c0v = c0[(size_t)r * H_SZ + jj];
                float f  = acc[m][0][i] + bf;
                float ig = acc[m][1][i] + bi;
                float o  = acc[m][2][i] + bo;
                float g  = acc[m][3][i] + bg;
                float cn = hsig(f) * c0v + hsig(ig) * htanh(g);
                h1out[(size_t)r * H_SZ + jj] = hsig(o) * htanh(cn);
                c1out[(size_t)r * H_SZ + jj] = cn;
            }
        }
}

// ---------------------------------------------------------------------------
extern "C" void kernel_launch(void* const* d_in, const int* in_sizes, int n_in,
                              void* d_out, int out_size, void* d_ws, size_t ws_size,
                              hipStream_t stream)
{
    const float* x   = (const float*)d_in[0];  // [4096,2048]
    const float* h0  = (const float*)d_in[1];  // [4096,2048]
    const float* c0  = (const float*)d_in[2];  // [4096,2048]
    const float* Wih = (const float*)d_in[3];  // [8192,2048]
    const float* Whh = (const float*)d_in[4];  // [8192,2048]
    const float* bhh = (const float*)d_in[5];  // [8192]
    float* out = (float*)d_out;                // h1 (8M) ++ c1 (8M) fp32

    // workspace: X' bf16 32MB | W' bf16 64MB
    if (ws_size < (size_t)96 * 1024 * 1024) return;
    char* ws = (char*)d_ws;
    __hip_bfloat16* Xp = (__hip_bfloat16*)ws;
    __hip_bfloat16* Wp = (__hip_bfloat16*)(ws + (size_t)32 * 1024 * 1024);

    cvt_all_kernel<<<2048, 256, 0, stream>>>(x, h0, Wih, Whh, Xp, Wp);
    gemm_fused_kernel<<<512, 512, 131072, stream>>>(Xp, Wp, c0, bhh, out);
}

// Round 13
// 472.053 us; speedup vs baseline: 2.2694x; 1.0399x over previous
//
#include <hip/hip_runtime.h>
#include <hip/hip_bf16.h>

// ---------------------------------------------------------------------------
// QLSTMCell MI355X round 13:
//  - carries: 256x256xBK64, 8 waves, gate-permuted W', fused cell epilogue,
//    chunk^row swizzle (conflicts=0), single fused cvt kernel
//  - delta: 2-barrier/K-tile free-run schedule. Each barrier is preceded by
//    the vmcnt guard for exactly the halves read after it (per-wave guard +
//    barrier = global guarantee). Waves free-run between barriers so one
//    wave's ds_reads overlap another's MFMA block (read||MFMA overlap).
// vmcnt LEDGER (1 gload/thread per stage unit; FIFO):
//   burst1(T) = a0,a1,b0,b1 (A-h0+B-h0 of tile T); burst2(T) = b2,b3,a2,a3.
//   tile t issues burst1(t+1) at top, burst2(t+1) after mid barrier.
//   entry(t): outstanding = burst2(t) [4]       (issued during t-1)
//   top: +burst1(t+1) -> 8
//   mid: vmcnt(4) retires burst2(t) -> B-h1,A-h1(t) landed (own wave);
//        barrier -> landed for ALL waves; reads of bv1/aw now safe.
//   after mid: +burst2(t+1) -> 8
//   exit: vmcnt(4) retires burst1(t+1) (issued ~a tile earlier, free);
//        barrier -> A-h0,B-h0(t+1) globally landed; entry state = 4. ✓
//   prologue: stage tile0 (burst1,burst2), vmcnt(4) retires burst1(t0),
//        barrier -> entry state = burst2(t0) = 4. ✓
//   last tile: no issues; mid vmcnt(0) drains burst2(NT-1); exit no-op. ✓
// WAR: burst*(t+1) writes bufn, last ds_read in tile t-1 (as bufc); those
//   reads drained by each wave's lgkmcnt(0) before its m2, which precedes
//   exit(t-1) barrier, which precedes these issues. ✓
// RAW(ds): m0 needs av+bv0 -> lgkmcnt(0); m1 needs bv1 (first 4 of 12 issued)
//   -> lgkmcnt(8); m2/m3 need aw -> lgkmcnt(0). ✓
// ---------------------------------------------------------------------------

typedef __attribute__((ext_vector_type(8))) short short8;   // 8 x bf16
typedef __attribute__((ext_vector_type(4))) float f32x4;    // MFMA accum

#define B_SZ 4096
#define K_SZ 4096      // IN + H
#define N_SZ 8192      // 4*H
#define H_SZ 2048

typedef const __attribute__((address_space(1))) void gvoid_t;
typedef __attribute__((address_space(3))) void lvoid_t;

__device__ __forceinline__ void gload_lds16(const __hip_bfloat16* g, void* l) {
    __builtin_amdgcn_global_load_lds((gvoid_t*)g, (lvoid_t*)l, 16, 0, 0);
}

__device__ __forceinline__ float hsig(float x) {
    return fminf(fmaxf(x * (1.0f / 6.0f) + 0.5f, 0.0f), 1.0f);
}
__device__ __forceinline__ float htanh(float x) {
    return fminf(fmaxf(x, -1.0f), 1.0f);
}

__device__ __forceinline__ void cvt8_store(const float* src, __hip_bfloat16* dst) {
    float4 v0 = *reinterpret_cast<const float4*>(src);
    float4 v1 = *reinterpret_cast<const float4*>(src + 4);
    union { __hip_bfloat16 h[8]; uint4 q; } p;
    p.h[0] = __float2bfloat16(v0.x); p.h[1] = __float2bfloat16(v0.y);
    p.h[2] = __float2bfloat16(v0.z); p.h[3] = __float2bfloat16(v0.w);
    p.h[4] = __float2bfloat16(v1.x); p.h[5] = __float2bfloat16(v1.y);
    p.h[6] = __float2bfloat16(v1.z); p.h[7] = __float2bfloat16(v1.w);
    *reinterpret_cast<uint4*>(dst) = p.q;
}

// ---- single fused cvt kernel (unchanged from R12) --------------------------
__global__ void cvt_all_kernel(const float* __restrict__ x,
                               const float* __restrict__ h0,
                               const float* __restrict__ wih,
                               const float* __restrict__ whh,
                               __hip_bfloat16* __restrict__ Xp,
                               __hip_bfloat16* __restrict__ Wp)
{
    constexpr int XT = B_SZ * K_SZ / 8;   // 2M units
    constexpr int WT = N_SZ * K_SZ / 8;   // 4M units
    const int stride = gridDim.x * blockDim.x;
    for (int i = blockIdx.x * blockDim.x + threadIdx.x; i < XT + WT; i += stride) {
        if (i < XT) {
            int idx = i << 3;
            int r = idx >> 12;
            int c = idx & 4095;
            const float* src = (c < 2048) ? (x + (size_t)r * 2048 + c)
                                          : (h0 + (size_t)r * 2048 + (c - 2048));
            cvt8_store(src, Xp + idx);
        } else {
            int idx = (i - XT) << 3;
            int r = idx >> 12;
            int c = idx & 4095;
            int gate = (((r >> 7) & 1) << 1) | ((r >> 4) & 1);
            int j = (r & 15) | (((r >> 5) & 3) << 4) | ((r >> 8) << 6);
            int srow = gate * 2048 + j;
            const float* src = (c < 2048) ? (wih + (size_t)srow * 2048 + c)
                                          : (whh + (size_t)srow * 2048 + (c - 2048));
            cvt8_store(src, Wp + idx);
        }
    }
}

// ---- fused GEMM + LSTM cell, 2-barrier/K-tile free-run schedule ------------
__global__ __launch_bounds__(512, 2)
void gemm_fused_kernel(const __hip_bfloat16* __restrict__ A,
                       const __hip_bfloat16* __restrict__ Bw,
                       const float* __restrict__ c0,
                       const float* __restrict__ bias,
                       float* __restrict__ out)
{
    constexpr int BK = 64;
    constexpr int NT = K_SZ / BK;            // 64 K-tiles
    constexpr int NWG = (B_SZ / 256) * (N_SZ / 256);  // 512
    constexpr int TILEB = 65536;             // A 32KB + B 32KB per buffer

    extern __shared__ __align__(16) char lds[];   // 2 * TILEB = 128KB dynamic

    const int tid  = threadIdx.x;
    const int wave = tid >> 6;
    const int lane = tid & 63;
    const int wrow = wave >> 2;        // 0..1
    const int wcol = wave & 3;         // 0..3
    const int fr   = lane & 15;
    const int fkq  = lane >> 4;

    // XCD-aware bijective swizzle (NWG = 512, %8==0)
    int bid = blockIdx.x;
    int swz = (bid & 7) * (NWG / 8) + (bid >> 3);
    int bm = swz >> 5;                 // 0..15
    int bn = swz & 31;                 // 0..31

    // ---- staging (linear LDS dest; inverse-swizzled global source) ---------
    const int rs  = tid >> 3;          // 0..63 row within 64-row stage unit
    const int ch  = tid & 7;
    const int lch = ch ^ (rs & 7);
    const __hip_bfloat16* pa = A  + (size_t)(bm * 256 + rs) * K_SZ + lch * 8;
    const __hip_bfloat16* pb = Bw + (size_t)(bn * 256 + rs) * K_SZ + lch * 8;

#define STG_A(bufn, kt, srow) \
    gload_lds16(pa + (size_t)(srow) * K_SZ + (kt), (bufn) + (srow) * 128 + wave * 1024)
#define STG_B(bufn, kt, srow) \
    gload_lds16(pb + (size_t)(srow) * K_SZ + (kt), (bufn) + 32768 + (srow) * 128 + wave * 1024)
// burst1 = A-half0 + B-half0 ; burst2 = B-half1 + A-half1
#define STG_BURST1(bufn, kt) { \
    STG_A(bufn, kt, 0);   STG_A(bufn, kt, 64); \
    STG_B(bufn, kt, 0);   STG_B(bufn, kt, 64); }
#define STG_BURST2(bufn, kt) { \
    STG_B(bufn, kt, 128); STG_B(bufn, kt, 192); \
    STG_A(bufn, kt, 128); STG_A(bufn, kt, 192); }

    // ---- swizzled ds_read byte offsets (ks=0); ks=1 is ^64, mh/nh is +16384
    int a_off[4], b_off[2];
#pragma unroll
    for (int mf = 0; mf < 4; ++mf) {
        int row = wrow * 64 + mf * 16 + fr;
        a_off[mf] = row * 128 + ((fkq ^ (row & 7)) << 4);
    }
#pragma unroll
    for (int nf = 0; nf < 2; ++nf) {
        int row = wcol * 32 + nf * 16 + fr;
        b_off[nf] = row * 128 + ((fkq ^ (row & 7)) << 4);
    }

    f32x4 acc[8][4];
#pragma unroll
    for (int m = 0; m < 8; ++m)
#pragma unroll
        for (int n = 0; n < 4; ++n)
            acc[m][n] = f32x4{0.f, 0.f, 0.f, 0.f};

    // ---- prologue: stage tile 0; guard burst1; barrier ----------------------
    STG_BURST1(lds, 0);
    STG_BURST2(lds, 0);
    asm volatile("s_waitcnt vmcnt(4)" ::: "memory");   // burst1(t0) landed
    asm volatile("s_barrier" ::: "memory");            // globally landed

#pragma unroll 1
    for (int t = 0; t < NT; ++t) {
        char* bufc = lds + (t & 1) * TILEB;
        char* bufn = lds + ((t + 1) & 1) * TILEB;
        const char* Ab = bufc;
        const char* Bb = bufc + 32768;
        const int ktn = (t + 1) * BK;
        const bool st = (t + 1 < NT);

        // ===== window 1: A-h0/B-h0 reads + MFMA m0 (mh0,nh0..nh1? no: nh0) ==
        if (st) STG_BURST1(bufn, ktn);                 // vm: 4 -> 8
        short8 av[4][2], bv0[2][2];
#pragma unroll
        for (int mf = 0; mf < 4; ++mf)
#pragma unroll
            for (int ks = 0; ks < 2; ++ks)
                av[mf][ks] = *(const short8*)(Ab + (a_off[mf] ^ (ks << 6)));
#pragma unroll
        for (int nf = 0; nf < 2; ++nf)
#pragma unroll
            for (int ks = 0; ks < 2; ++ks)
                bv0[nf][ks] = *(const short8*)(Bb + (b_off[nf] ^ (ks << 6)));
        asm volatile("s_waitcnt lgkmcnt(0)" ::: "memory");
        __builtin_amdgcn_sched_barrier(0);
        __builtin_amdgcn_s_setprio(1);
#pragma unroll
        for (int mf = 0; mf < 4; ++mf)
#pragma unroll
            for (int nf = 0; nf < 2; ++nf)
#pragma unroll
                for (int ks = 0; ks < 2; ++ks)
                    acc[mf][nf] = __builtin_amdgcn_mfma_f32_16x16x32_bf16(av[mf][ks], bv0[nf][ks], acc[mf][nf], 0, 0, 0);
        __builtin_amdgcn_s_setprio(0);

        // ===== mid guard: burst2(t) (B-h1, A-h1) must be globally landed ====
        if (st) asm volatile("s_waitcnt vmcnt(4)" ::: "memory");
        else    asm volatile("s_waitcnt vmcnt(0)" ::: "memory");
        asm volatile("s_barrier" ::: "memory");

        // ===== window 2: B-h1/A-h1 reads + MFMA m1,m2,m3 (48 MFMA) ==========
        if (st) STG_BURST2(bufn, ktn);                 // vm: 4 -> 8
        short8 bv1[2][2], aw[4][2];
#pragma unroll
        for (int nf = 0; nf < 2; ++nf)
#pragma unroll
            for (int ks = 0; ks < 2; ++ks)
                bv1[nf][ks] = *(const short8*)(Bb + 16384 + (b_off[nf] ^ (ks << 6)));
#pragma unroll
        for (int mf = 0; mf < 4; ++mf)
#pragma unroll
            for (int ks = 0; ks < 2; ++ks)
                aw[mf][ks] = *(const short8*)(Ab + 16384 + (a_off[mf] ^ (ks << 6)));
        asm volatile("s_waitcnt lgkmcnt(8)" ::: "memory");   // bv1 (first 4) landed
        __builtin_amdgcn_sched_barrier(0);
        __builtin_amdgcn_s_setprio(1);
#pragma unroll
        for (int mf = 0; mf < 4; ++mf)      // m1: (mh0, nh1) — aw still in flight
#pragma unroll
            for (int nf = 0; nf < 2; ++nf)
#pragma unroll
                for (int ks = 0; ks < 2; ++ks)
                    acc[mf][2 + nf] = __builtin_amdgcn_mfma_f32_16x16x32_bf16(av[mf][ks], bv1[nf][ks], acc[mf][2 + nf], 0, 0, 0);
        __builtin_amdgcn_s_setprio(0);
        asm volatile("s_waitcnt lgkmcnt(0)" ::: "memory");   // aw landed
        __builtin_amdgcn_sched_barrier(0);
        __builtin_amdgcn_s_setprio(1);
#pragma unroll
        for (int mf = 0; mf < 4; ++mf)      // m2: (mh1, nh0)
#pragma unroll
            for (int nf = 0; nf < 2; ++nf)
#pragma unroll
                for (int ks = 0; ks < 2; ++ks)
                    acc[4 + mf][nf] = __builtin_amdgcn_mfma_f32_16x16x32_bf16(aw[mf][ks], bv0[nf][ks], acc[4 + mf][nf], 0, 0, 0);
#pragma unroll
        for (int mf = 0; mf < 4; ++mf)      // m3: (mh1, nh1)
#pragma unroll
            for (int nf = 0; nf < 2; ++nf)
#pragma unroll
                for (int ks = 0; ks < 2; ++ks)
                    acc[4 + mf][2 + nf] = __builtin_amdgcn_mfma_f32_16x16x32_bf16(aw[mf][ks], bv1[nf][ks], acc[4 + mf][2 + nf], 0, 0, 0);
        __builtin_amdgcn_s_setprio(0);

        // ===== exit guard: burst1(t+1) (A-h0,B-h0) globally landed ==========
        if (st) asm volatile("s_waitcnt vmcnt(4)" ::: "memory");
        asm volatile("s_barrier" ::: "memory");
    }
#undef STG_A
#undef STG_B
#undef STG_BURST1
#undef STG_BURST2

    // ---- fused LSTM-cell epilogue (acc n-index == gate: 0=f,1=i,2=o,3=g) ---
    const int jj = bn * 64 + wcol * 16 + fr;         // 0..2047
    const float bf = bias[jj];
    const float bi = bias[2048 + jj];
    const float bo = bias[4096 + jj];
    const float bg = bias[6144 + jj];
    float* h1out = out;
    float* c1out = out + (size_t)B_SZ * H_SZ;
#pragma unroll
    for (int mh = 0; mh < 2; ++mh)
#pragma unroll
        for (int mf = 0; mf < 4; ++mf) {
            const int m = mh * 4 + mf;
            const int row0 = bm * 256 + mh * 128 + wrow * 64 + mf * 16 + fkq * 4;
#pragma unroll
            for (int i = 0; i < 4; ++i) {
                int r = row0 + i;
                float c0v = c0[(size_t)r * H_SZ + jj];
                float f  = acc[m][0][i] + bf;
                float ig = acc[m][1][i] + bi;
                float o  = acc[m][2][i] + bo;
                float g  = acc[m][3][i] + bg;
                float cn = hsig(f) * c0v + hsig(ig) * htanh(g);
                h1out[(size_t)r * H_SZ + jj] = hsig(o) * htanh(cn);
                c1out[(size_t)r * H_SZ + jj] = cn;
            }
        }
}

// ---------------------------------------------------------------------------
extern "C" void kernel_launch(void* const* d_in, const int* in_sizes, int n_in,
                              void* d_out, int out_size, void* d_ws, size_t ws_size,
                              hipStream_t stream)
{
    const float* x   = (const float*)d_in[0];  // [4096,2048]
    const float* h0  = (const float*)d_in[1];  // [4096,2048]
    const float* c0  = (const float*)d_in[2];  // [4096,2048]
    const float* Wih = (const float*)d_in[3];  // [8192,2048]
    const float* Whh = (const float*)d_in[4];  // [8192,2048]
    const float* bhh = (const float*)d_in[5];  // [8192]
    float* out = (float*)d_out;                // h1 (8M) ++ c1 (8M) fp32

    // workspace: X' bf16 32MB | W' bf16 64MB
    if (ws_size < (size_t)96 * 1024 * 1024) return;
    char* ws = (char*)d_ws;
    __hip_bfloat16* Xp = (__hip_bfloat16*)ws;
    __hip_bfloat16* Wp = (__hip_bfloat16*)(ws + (size_t)32 * 1024 * 1024);

    cvt_all_kernel<<<2048, 256, 0, stream>>>(x, h0, Wih, Whh, Xp, Wp);
    gemm_fused_kernel<<<512, 512, 131072, stream>>>(Xp, Wp, c0, bhh, out);
}